// Round 3
// baseline (4226.961 us; speedup 1.0000x reference)
//
#include <hip/hip_runtime.h>
#include <hip/hip_fp16.h>

#define N_NODES 100000
#define N_EDGES 1600000
#define HID 128
#define N_GRAPHS 512
#define SCAN_B 256

// ---------------- CSR build: histogram / scan / scatter ----------------

__global__ void k_hist(const int* __restrict__ dst, int e, int* __restrict__ cnt) {
    int i = blockIdx.x * 256 + threadIdx.x;
    if (i < e) atomicAdd(&cnt[dst[i]], 1);
}

__global__ void k_deg_fin(const int* __restrict__ cnt, float* __restrict__ dis,
                          float* __restrict__ dinv, int n) {
    int i = blockIdx.x * 256 + threadIdx.x;
    if (i < n) {
        float d = (float)(cnt[i] + 1);   // +1 self-loop
        dis[i] = rsqrtf(d);
        dinv[i] = 1.0f / d;
    }
}

__global__ void k_scan1(const int* __restrict__ cnt, int* __restrict__ pre,
                        int* __restrict__ bsum, int n) {
    __shared__ int s[SCAN_B];
    int t = threadIdx.x;
    int i = blockIdx.x * SCAN_B + t;
    int v = (i < n) ? cnt[i] : 0;
    s[t] = v;
    __syncthreads();
    for (int off = 1; off < SCAN_B; off <<= 1) {
        int u = (t >= off) ? s[t - off] : 0;
        __syncthreads();
        s[t] += u;
        __syncthreads();
    }
    if (i < n) pre[i] = s[t] - v;                     // exclusive
    if (t == SCAN_B - 1) bsum[blockIdx.x] = s[t];     // block total
}

__global__ void k_scan2(int* __restrict__ bsum, int nb) {
    __shared__ int s[512];
    int t = threadIdx.x;
    int v = (t < nb) ? bsum[t] : 0;
    s[t] = v;
    __syncthreads();
    for (int off = 1; off < 512; off <<= 1) {
        int u = (t >= off) ? s[t - off] : 0;
        __syncthreads();
        s[t] += u;
        __syncthreads();
    }
    if (t < nb) bsum[t] = s[t] - v;                   // exclusive
}

__global__ void k_scan3(int* __restrict__ pre, const int* __restrict__ bsum,
                        int* __restrict__ cursor, int n, int e) {
    int i = blockIdx.x * SCAN_B + threadIdx.x;
    if (i < n) {
        int r = pre[i] + bsum[blockIdx.x];
        pre[i] = r;
        cursor[i] = r;
    }
    if (i == 0) pre[n] = e;
}

__global__ void k_scatter(const int* __restrict__ ei, const float* __restrict__ dis,
                          int* __restrict__ cursor, int* __restrict__ csrc,
                          float* __restrict__ cw, int e) {
    int i = blockIdx.x * 256 + threadIdx.x;
    if (i >= e) return;
    int s = ei[i];
    int d = ei[N_EDGES + i];
    int pos = atomicAdd(&cursor[d], 1);
    csrc[pos] = s;
    cw[pos] = dis[s] * dis[d];
}

// ---------------- layer 1: x (N x 7) @ W1 (7 x 128) -> fp16 ----------------

__global__ void k_linear1(const float* __restrict__ x, const float* __restrict__ W1,
                          __half* __restrict__ hw, int n) {
    __shared__ float W1s[7 * 128];
    int tid = threadIdx.x;
    for (int i = tid; i < 7 * 128; i += 256) W1s[i] = W1[i];
    __syncthreads();
    int node = blockIdx.x * 2 + (tid >> 7);
    if (node >= n) return;
    int c = tid & 127;
    const float* xr = x + (size_t)node * 7;
    float acc = 0.f;
#pragma unroll
    for (int k = 0; k < 7; ++k) acc += xr[k] * W1s[k * 128 + c];
    hw[(size_t)node * 128 + c] = __float2half_rn(acc);
}

// ---------------- gather aggregation (fp16 rows) ----------------
// agg[d] = hw[d]*dinv[d] + sum_s hw[s]*w ; one wave per node, half2 per lane

__launch_bounds__(256) __global__
void k_gather(const int* __restrict__ rowptr, const int* __restrict__ csrc,
              const float* __restrict__ cw, const float* __restrict__ dinv,
              const __half2* __restrict__ hw2, __half2* __restrict__ agg2, int n) {
    int node = blockIdx.x * 4 + (threadIdx.x >> 6);
    if (node >= n) return;
    int lane = threadIdx.x & 63;
    int beg = rowptr[node];
    int end = rowptr[node + 1];
    float di = dinv[node];
    float2 hv = __half22float2(hw2[(size_t)node * 64 + lane]);
    float2 acc;
    acc.x = hv.x * di;
    acc.y = hv.y * di;
    int j = beg;
    for (; j + 3 < end; j += 4) {
        int s0 = csrc[j], s1 = csrc[j + 1], s2 = csrc[j + 2], s3 = csrc[j + 3];
        float w0 = cw[j], w1 = cw[j + 1], w2 = cw[j + 2], w3 = cw[j + 3];
        float2 v0 = __half22float2(hw2[(size_t)s0 * 64 + lane]);
        float2 v1 = __half22float2(hw2[(size_t)s1 * 64 + lane]);
        float2 v2 = __half22float2(hw2[(size_t)s2 * 64 + lane]);
        float2 v3 = __half22float2(hw2[(size_t)s3 * 64 + lane]);
        acc.x += v0.x * w0 + v1.x * w1 + v2.x * w2 + v3.x * w3;
        acc.y += v0.y * w0 + v1.y * w1 + v2.y * w2 + v3.y * w3;
    }
    for (; j < end; ++j) {
        int s0 = csrc[j];
        float w0 = cw[j];
        float2 v0 = __half22float2(hw2[(size_t)s0 * 64 + lane]);
        acc.x += v0.x * w0;
        acc.y += v0.y * w0;
    }
    agg2[(size_t)node * 64 + lane] = __floats2half2_rn(acc.x, acc.y);
}

// ---------------- fused relu(agg+b) @ W (128x128), 4-node register blocking ----------------
// 32 nodes per block pass; thread = (slot 0..7) x (cg 0..31); 4 nodes x 4 channels each.

__launch_bounds__(256, 2) __global__
void k_gemm128_fused(const __half* __restrict__ aggin, const float* __restrict__ b,
                     const float* __restrict__ W, __half* __restrict__ hwout, int n) {
    __shared__ float Ws[128 * 128];   // 64 KB
    __shared__ float hs[32][128];     // 16 KB  (total exactly 80 KB -> 2 blocks/CU)
    int tid = threadIdx.x;
    for (int i = tid; i < 128 * 32; i += 256) ((float4*)Ws)[i] = ((const float4*)W)[i];

    int lr  = tid >> 3;        // 0..31 local row (load phase)
    int lcq = tid & 7;         // 16-channel chunk (load phase)
    float4 bb0 = ((const float4*)b)[lcq * 4 + 0];
    float4 bb1 = ((const float4*)b)[lcq * 4 + 1];
    float4 bb2 = ((const float4*)b)[lcq * 4 + 2];
    float4 bb3 = ((const float4*)b)[lcq * 4 + 3];

    int cg = tid & 31;         // channel float4 group (compute phase)
    int slot = tid >> 5;       // 0..7 -> nodes slot*4..slot*4+3

    for (int base = blockIdx.x * 32; base < n; base += gridDim.x * 32) {
        __syncthreads();   // prev compute done (and W staged, first iter)
        int gn = base + lr;
        float4 f0, f1, f2, f3;
        if (gn < n) {
            const uint4* src = (const uint4*)(aggin + (size_t)gn * 128 + lcq * 16);
            uint4 p0 = src[0];
            uint4 p1 = src[1];
            float2 t0 = __half22float2(*(const __half2*)&p0.x);
            float2 t1 = __half22float2(*(const __half2*)&p0.y);
            float2 t2 = __half22float2(*(const __half2*)&p0.z);
            float2 t3 = __half22float2(*(const __half2*)&p0.w);
            float2 t4 = __half22float2(*(const __half2*)&p1.x);
            float2 t5 = __half22float2(*(const __half2*)&p1.y);
            float2 t6 = __half22float2(*(const __half2*)&p1.z);
            float2 t7 = __half22float2(*(const __half2*)&p1.w);
            f0 = make_float4(fmaxf(t0.x + bb0.x, 0.f), fmaxf(t0.y + bb0.y, 0.f),
                             fmaxf(t1.x + bb0.z, 0.f), fmaxf(t1.y + bb0.w, 0.f));
            f1 = make_float4(fmaxf(t2.x + bb1.x, 0.f), fmaxf(t2.y + bb1.y, 0.f),
                             fmaxf(t3.x + bb1.z, 0.f), fmaxf(t3.y + bb1.w, 0.f));
            f2 = make_float4(fmaxf(t4.x + bb2.x, 0.f), fmaxf(t4.y + bb2.y, 0.f),
                             fmaxf(t5.x + bb2.z, 0.f), fmaxf(t5.y + bb2.w, 0.f));
            f3 = make_float4(fmaxf(t6.x + bb3.x, 0.f), fmaxf(t6.y + bb3.y, 0.f),
                             fmaxf(t7.x + bb3.z, 0.f), fmaxf(t7.y + bb3.w, 0.f));
        } else {
            f0 = f1 = f2 = f3 = make_float4(0.f, 0.f, 0.f, 0.f);
        }
        float4* hr = (float4*)&hs[lr][lcq * 16];
        hr[0] = f0; hr[1] = f1; hr[2] = f2; hr[3] = f3;
        __syncthreads();

        const float* h0 = hs[slot * 4 + 0];
        const float* h1 = hs[slot * 4 + 1];
        const float* h2 = hs[slot * 4 + 2];
        const float* h3 = hs[slot * 4 + 3];
        float4 acc0 = make_float4(0.f,0.f,0.f,0.f);
        float4 acc1 = acc0, acc2 = acc0, acc3 = acc0;
#pragma unroll
        for (int k = 0; k < 128; k += 4) {
            float4 w0 = ((const float4*)Ws)[(k + 0) * 32 + cg];
            float4 w1 = ((const float4*)Ws)[(k + 1) * 32 + cg];
            float4 w2 = ((const float4*)Ws)[(k + 2) * 32 + cg];
            float4 w3 = ((const float4*)Ws)[(k + 3) * 32 + cg];
            float4 a0 = *(const float4*)&h0[k];
            float4 a1 = *(const float4*)&h1[k];
            float4 a2 = *(const float4*)&h2[k];
            float4 a3 = *(const float4*)&h3[k];
            acc0.x += a0.x*w0.x + a0.y*w1.x + a0.z*w2.x + a0.w*w3.x;
            acc0.y += a0.x*w0.y + a0.y*w1.y + a0.z*w2.y + a0.w*w3.y;
            acc0.z += a0.x*w0.z + a0.y*w1.z + a0.z*w2.z + a0.w*w3.z;
            acc0.w += a0.x*w0.w + a0.y*w1.w + a0.z*w2.w + a0.w*w3.w;
            acc1.x += a1.x*w0.x + a1.y*w1.x + a1.z*w2.x + a1.w*w3.x;
            acc1.y += a1.x*w0.y + a1.y*w1.y + a1.z*w2.y + a1.w*w3.y;
            acc1.z += a1.x*w0.z + a1.y*w1.z + a1.z*w2.z + a1.w*w3.z;
            acc1.w += a1.x*w0.w + a1.y*w1.w + a1.z*w2.w + a1.w*w3.w;
            acc2.x += a2.x*w0.x + a2.y*w1.x + a2.z*w2.x + a2.w*w3.x;
            acc2.y += a2.x*w0.y + a2.y*w1.y + a2.z*w2.y + a2.w*w3.y;
            acc2.z += a2.x*w0.z + a2.y*w1.z + a2.z*w2.z + a2.w*w3.z;
            acc2.w += a2.x*w0.w + a2.y*w1.w + a2.z*w2.w + a2.w*w3.w;
            acc3.x += a3.x*w0.x + a3.y*w1.x + a3.z*w2.x + a3.w*w3.x;
            acc3.y += a3.x*w0.y + a3.y*w1.y + a3.z*w2.y + a3.w*w3.y;
            acc3.z += a3.x*w0.z + a3.y*w1.z + a3.z*w2.z + a3.w*w3.z;
            acc3.w += a3.x*w0.w + a3.y*w1.w + a3.z*w2.w + a3.w*w3.w;
        }
        float4 accs[4] = {acc0, acc1, acc2, acc3};
#pragma unroll
        for (int m = 0; m < 4; ++m) {
            int on = base + slot * 4 + m;
            if (on < n) {
                __half2 lo = __floats2half2_rn(accs[m].x, accs[m].y);
                __half2 hi = __floats2half2_rn(accs[m].z, accs[m].w);
                uint2 pk;
                pk.x = *(unsigned*)&lo;
                pk.y = *(unsigned*)&hi;
                *(uint2*)(hwout + (size_t)on * 128 + cg * 4) = pk;
            }
        }
    }
}

// ---------------- pooling: segment_max(relu(agg+b)) via atomicMax on float bits ----------------

__global__ void k_pool_max(const __half* __restrict__ agg, const float* __restrict__ b,
                           const int* __restrict__ batch, unsigned* __restrict__ pooled, int n) {
    int idx = blockIdx.x * 256 + threadIdx.x;
    int node = idx >> 7;
    if (node >= n) return;
    int c = idx & 127;
    int g = batch[node];
    float v = __half2float(agg[(size_t)node * 128 + c]) + b[c];
    v = fmaxf(v, 0.f);
    atomicMax(&pooled[(size_t)g * 128 + c], __float_as_uint(v));
}

// ---------------- head: out[g] = pooled[g] @ Wl + bl ----------------

__global__ void k_final(const float* __restrict__ pooled, const float* __restrict__ Wl,
                        const float* __restrict__ bl, float* __restrict__ out) {
    int g = blockIdx.x;
    int t = threadIdx.x;  // 64 threads
    float p0 = pooled[(size_t)g * 128 + t];
    float p1 = pooled[(size_t)g * 128 + t + 64];
    float a0 = p0 * Wl[t * 2 + 0] + p1 * Wl[(t + 64) * 2 + 0];
    float a1 = p0 * Wl[t * 2 + 1] + p1 * Wl[(t + 64) * 2 + 1];
#pragma unroll
    for (int off = 32; off > 0; off >>= 1) {
        a0 += __shfl_down(a0, off);
        a1 += __shfl_down(a1, off);
    }
    if (t == 0) {
        out[g * 2 + 0] = a0 + bl[0];
        out[g * 2 + 1] = a1 + bl[1];
    }
}

// ---------------- launch ----------------

extern "C" void kernel_launch(void* const* d_in, const int* in_sizes, int n_in,
                              void* d_out, int out_size, void* d_ws, size_t ws_size,
                              hipStream_t stream) {
    const float* x  = (const float*)d_in[0];
    const int*   ei = (const int*)d_in[1];
    const int*   batch = (const int*)d_in[2];
    const float* W1 = (const float*)d_in[3];
    const float* b1 = (const float*)d_in[4];
    const float* W2 = (const float*)d_in[5];
    const float* b2 = (const float*)d_in[6];
    const float* W3 = (const float*)d_in[7];
    const float* b3 = (const float*)d_in[8];
    const float* Wl = (const float*)d_in[9];
    const float* bl = (const float*)d_in[10];
    float* out = (float*)d_out;

    const int N = N_NODES, E = N_EDGES;

    // workspace layout
    char* ws = (char*)d_ws;
    __half* bufA = (__half*)ws;                             // N*128 fp16 (hw)
    __half* bufB = bufA + (size_t)N * 128;                  // N*128 fp16 (agg)
    unsigned* pooled = (unsigned*)(bufB + (size_t)N * 128); // G*128
    float* dis  = (float*)(pooled + (size_t)N_GRAPHS * 128);
    float* dinv = dis + N;
    int*   cnt  = (int*)(dinv + N);                         // N
    int*   rowptr = cnt + N;                                // N+1
    int*   cursor = rowptr + N + 2;                         // N
    int*   bsum   = cursor + N;                             // 512
    int*   csrc   = bsum + 512;                             // E
    float* cw     = (float*)(csrc + E);                     // E

    int nb256 = (N + 255) / 256;   // 391
    int eb256 = (E + 255) / 256;   // 6250

    // CSR build + norms
    hipMemsetAsync(cnt, 0, (size_t)N * sizeof(int), stream);
    k_hist<<<eb256, 256, 0, stream>>>(ei + E, E, cnt);
    k_deg_fin<<<nb256, 256, 0, stream>>>(cnt, dis, dinv, N);
    k_scan1<<<nb256, SCAN_B, 0, stream>>>(cnt, rowptr, bsum, N);
    k_scan2<<<1, 512, 0, stream>>>(bsum, nb256);
    k_scan3<<<nb256, SCAN_B, 0, stream>>>(rowptr, bsum, cursor, N, E);
    k_scatter<<<eb256, 256, 0, stream>>>(ei, dis, cursor, csrc, cw, E);

    int ggrid = (N + 3) / 4;
    int gemm_grid = 1024;

    // layer 1
    k_linear1<<<(N + 1) / 2, 256, 0, stream>>>(x, W1, bufA, N);
    k_gather<<<ggrid, 256, 0, stream>>>(rowptr, csrc, cw, dinv,
                                        (const __half2*)bufA, (__half2*)bufB, N);

    // layer 2
    k_gemm128_fused<<<gemm_grid, 256, 0, stream>>>(bufB, b1, W2, bufA, N);
    k_gather<<<ggrid, 256, 0, stream>>>(rowptr, csrc, cw, dinv,
                                        (const __half2*)bufA, (__half2*)bufB, N);

    // layer 3
    k_gemm128_fused<<<gemm_grid, 256, 0, stream>>>(bufB, b2, W3, bufA, N);
    k_gather<<<ggrid, 256, 0, stream>>>(rowptr, csrc, cw, dinv,
                                        (const __half2*)bufA, (__half2*)bufB, N);

    // pooling
    hipMemsetAsync(pooled, 0, (size_t)N_GRAPHS * 128 * sizeof(unsigned), stream);
    k_pool_max<<<(N * 128 + 255) / 256, 256, 0, stream>>>(bufB, b3, batch, pooled, N);

    // head
    k_final<<<N_GRAPHS, 64, 0, stream>>>((const float*)pooled, Wl, bl, out);
}

// Round 5
// 629.755 us; speedup vs baseline: 6.7121x; 6.7121x over previous
//
#include <hip/hip_runtime.h>
#include <hip/hip_fp16.h>

#define N_NODES 100000
#define N_EDGES 1600000
#define HID 128
#define N_GRAPHS 512
#define SCAN_B 256

typedef _Float16 f16x8 __attribute__((ext_vector_type(8)));
typedef float f32x4 __attribute__((ext_vector_type(4)));

// ---------------- CSR build: histogram / scan / scatter ----------------

__global__ void k_hist(const int* __restrict__ dst, int e, int* __restrict__ cnt) {
    int i = blockIdx.x * 256 + threadIdx.x;
    if (i < e) atomicAdd(&cnt[dst[i]], 1);
}

__global__ void k_deg_fin(const int* __restrict__ cnt, float* __restrict__ dis,
                          float* __restrict__ dinv, int n) {
    int i = blockIdx.x * 256 + threadIdx.x;
    if (i < n) {
        float d = (float)(cnt[i] + 1);   // +1 self-loop
        dis[i] = rsqrtf(d);
        dinv[i] = 1.0f / d;
    }
}

__global__ void k_scan1(const int* __restrict__ cnt, int* __restrict__ pre,
                        int* __restrict__ bsum, int n) {
    __shared__ int s[SCAN_B];
    int t = threadIdx.x;
    int i = blockIdx.x * SCAN_B + t;
    int v = (i < n) ? cnt[i] : 0;
    s[t] = v;
    __syncthreads();
    for (int off = 1; off < SCAN_B; off <<= 1) {
        int u = (t >= off) ? s[t - off] : 0;
        __syncthreads();
        s[t] += u;
        __syncthreads();
    }
    if (i < n) pre[i] = s[t] - v;                     // exclusive
    if (t == SCAN_B - 1) bsum[blockIdx.x] = s[t];     // block total
}

__global__ void k_scan2(int* __restrict__ bsum, int nb) {
    __shared__ int s[512];
    int t = threadIdx.x;
    int v = (t < nb) ? bsum[t] : 0;
    s[t] = v;
    __syncthreads();
    for (int off = 1; off < 512; off <<= 1) {
        int u = (t >= off) ? s[t - off] : 0;
        __syncthreads();
        s[t] += u;
        __syncthreads();
    }
    if (t < nb) bsum[t] = s[t] - v;                   // exclusive
}

__global__ void k_scan3(int* __restrict__ pre, const int* __restrict__ bsum,
                        int* __restrict__ cursor, int n, int e) {
    int i = blockIdx.x * SCAN_B + threadIdx.x;
    if (i < n) {
        int r = pre[i] + bsum[blockIdx.x];
        pre[i] = r;
        cursor[i] = r;
    }
    if (i == 0) pre[n] = e;
}

__global__ void k_scatter(const int* __restrict__ ei, const float* __restrict__ dis,
                          int* __restrict__ cursor, int* __restrict__ csrc,
                          float* __restrict__ cw, int e) {
    int i = blockIdx.x * 256 + threadIdx.x;
    if (i >= e) return;
    int s = ei[i];
    int d = ei[N_EDGES + i];
    int pos = atomicAdd(&cursor[d], 1);
    csrc[pos] = s;
    cw[pos] = dis[s] * dis[d];
}

// ---------------- layer 1: x (N x 7) @ W1 (7 x 128) -> fp16 ----------------

__global__ void k_linear1(const float* __restrict__ x, const float* __restrict__ W1,
                          __half* __restrict__ hw, int n) {
    __shared__ float W1s[7 * 128];
    int tid = threadIdx.x;
    for (int i = tid; i < 7 * 128; i += 256) W1s[i] = W1[i];
    __syncthreads();
    int node = blockIdx.x * 2 + (tid >> 7);
    if (node >= n) return;
    int c = tid & 127;
    const float* xr = x + (size_t)node * 7;
    float acc = 0.f;
#pragma unroll
    for (int k = 0; k < 7; ++k) acc += xr[k] * W1s[k * 128 + c];
    hw[(size_t)node * 128 + c] = __float2half_rn(acc);
}

// ---------------- gather aggregation (fp16 rows) ----------------
// agg[d] = hw[d]*dinv[d] + sum_s hw[s]*w ; one wave per node, half2 per lane

__launch_bounds__(256) __global__
void k_gather(const int* __restrict__ rowptr, const int* __restrict__ csrc,
              const float* __restrict__ cw, const float* __restrict__ dinv,
              const __half2* __restrict__ hw2, __half2* __restrict__ agg2, int n) {
    int node = blockIdx.x * 4 + (threadIdx.x >> 6);
    if (node >= n) return;
    int lane = threadIdx.x & 63;
    int beg = rowptr[node];
    int end = rowptr[node + 1];
    float di = dinv[node];
    float2 hv = __half22float2(hw2[(size_t)node * 64 + lane]);
    float2 acc;
    acc.x = hv.x * di;
    acc.y = hv.y * di;
    int j = beg;
    for (; j + 3 < end; j += 4) {
        int s0 = csrc[j], s1 = csrc[j + 1], s2 = csrc[j + 2], s3 = csrc[j + 3];
        float w0 = cw[j], w1 = cw[j + 1], w2 = cw[j + 2], w3 = cw[j + 3];
        float2 v0 = __half22float2(hw2[(size_t)s0 * 64 + lane]);
        float2 v1 = __half22float2(hw2[(size_t)s1 * 64 + lane]);
        float2 v2 = __half22float2(hw2[(size_t)s2 * 64 + lane]);
        float2 v3 = __half22float2(hw2[(size_t)s3 * 64 + lane]);
        acc.x += v0.x * w0 + v1.x * w1 + v2.x * w2 + v3.x * w3;
        acc.y += v0.y * w0 + v1.y * w1 + v2.y * w2 + v3.y * w3;
    }
    for (; j < end; ++j) {
        int s0 = csrc[j];
        float w0 = cw[j];
        float2 v0 = __half22float2(hw2[(size_t)s0 * 64 + lane]);
        acc.x += v0.x * w0;
        acc.y += v0.y * w0;
    }
    agg2[(size_t)node * 64 + lane] = __floats2half2_rn(acc.x, acc.y);
}

// ---------------- MFMA GEMM: hwout = relu(aggin + b) @ W  (fp16 in/out) ----------------
// Block = 256 threads = 4 waves; W^T staged once in LDS, then TWO 64-row
// A-tiles processed (128 rows/block). XOR swizzle kills stride-256B bank
// conflicts for ds_read_b128 fragment loads.
// A-tile rows >= n are ZERO-FILLED (NOT read): the OOB read of poisoned
// workspace was the R4 post-timing divergence — valid outputs must be a pure
// function of d_in + recomputed ws.
// mfma_f32_16x16x32_f16: lane l holds A[l&15][8*(l>>4)+i] / B[8*(l>>4)+i][l&15];
// C/D: col=lane&15, row=(lane>>4)*4+reg (guide-verified, dtype-independent).

__device__ __forceinline__ int swz(int row, int kByte) {
    return row * 256 + (kByte ^ ((row & 7) << 4));
}

__launch_bounds__(256) __global__
void k_gemm_mfma(const __half* __restrict__ aggin, const float* __restrict__ b,
                 const float* __restrict__ W, __half* __restrict__ hwout, int n) {
    __shared__ __align__(16) _Float16 Wt[128 * 128];  // 32 KB, Wt[n][k] swizzled
    __shared__ __align__(16) _Float16 As[64 * 128];   // 16 KB, As[m][k] swizzled
    int tid = threadIdx.x;

    // stage W^T (fp32 -> fp16), once per block; coalesced global, scalar LDS
    for (int i = tid; i < 128 * 128; i += 256) {
        int k = i >> 7;
        int nn = i & 127;
        *(_Float16*)((char*)Wt + swz(nn, k * 2)) = (_Float16)W[i];
    }

    int row = tid >> 2;        // 0..63 (A staging)
    int q = tid & 3;
    int wv = tid >> 6;
    int lane = tid & 63;
    int lo16 = lane & 15;
    int hi4 = lane >> 4;

    for (int t = 0; t < 2; ++t) {
        if (t) __syncthreads();   // all waves done reading As from tile t-1
        int grow = blockIdx.x * 128 + t * 64 + row;
#pragma unroll
        for (int j = 0; j < 4; ++j) {
            int c0 = q * 32 + j * 8;  // half index within row
            uint4 pk = make_uint4(0u, 0u, 0u, 0u);
            if (grow < n) {
                uint4 p = *(const uint4*)(aggin + (size_t)grow * 128 + c0);
                float4 bA = *(const float4*)(b + c0);
                float4 bB = *(const float4*)(b + c0 + 4);
                float2 t0 = __half22float2(*(const __half2*)&p.x);
                float2 t1 = __half22float2(*(const __half2*)&p.y);
                float2 t2 = __half22float2(*(const __half2*)&p.z);
                float2 t3 = __half22float2(*(const __half2*)&p.w);
                __half2 h0 = __floats2half2_rn(fmaxf(t0.x + bA.x, 0.f), fmaxf(t0.y + bA.y, 0.f));
                __half2 h1 = __floats2half2_rn(fmaxf(t1.x + bA.z, 0.f), fmaxf(t1.y + bA.w, 0.f));
                __half2 h2 = __floats2half2_rn(fmaxf(t2.x + bB.x, 0.f), fmaxf(t2.y + bB.y, 0.f));
                __half2 h3 = __floats2half2_rn(fmaxf(t3.x + bB.z, 0.f), fmaxf(t3.y + bB.w, 0.f));
                pk.x = *(unsigned*)&h0; pk.y = *(unsigned*)&h1;
                pk.z = *(unsigned*)&h2; pk.w = *(unsigned*)&h3;
            }
            *(uint4*)((char*)As + swz(row, c0 * 2)) = pk;
        }
        __syncthreads();   // As (and W on t=0) visible to all waves

        f32x4 acc[8];
#pragma unroll
        for (int nt = 0; nt < 8; ++nt) acc[nt] = (f32x4){0.f, 0.f, 0.f, 0.f};

        const char* Ab = (const char*)As;
        const char* Bb = (const char*)Wt;
#pragma unroll
        for (int kt = 0; kt < 4; ++kt) {
            int kByte = kt * 64 + hi4 * 16;
            f16x8 af = *(const f16x8*)(Ab + swz(wv * 16 + lo16, kByte));
#pragma unroll
            for (int nt = 0; nt < 8; ++nt) {
                f16x8 bf = *(const f16x8*)(Bb + swz(nt * 16 + lo16, kByte));
                acc[nt] = __builtin_amdgcn_mfma_f32_16x16x32_f16(af, bf, acc[nt], 0, 0, 0);
            }
        }

        int rbase = blockIdx.x * 128 + t * 64 + wv * 16 + hi4 * 4;
#pragma unroll
        for (int nt = 0; nt < 8; ++nt) {
#pragma unroll
            for (int r = 0; r < 4; ++r) {
                int node = rbase + r;
                if (node < n)
                    hwout[(size_t)node * 128 + nt * 16 + lo16] = __float2half_rn(acc[nt][r]);
            }
        }
    }
}

// ---------------- pooling: segment_max(relu(agg+b)) via atomicMax on float bits ----------------

__global__ void k_pool_max(const __half* __restrict__ agg, const float* __restrict__ b,
                           const int* __restrict__ batch, unsigned* __restrict__ pooled, int n) {
    int idx = blockIdx.x * 256 + threadIdx.x;
    int node = idx >> 7;
    if (node >= n) return;
    int c = idx & 127;
    int g = batch[node];
    float v = __half2float(agg[(size_t)node * 128 + c]) + b[c];
    v = fmaxf(v, 0.f);
    atomicMax(&pooled[(size_t)g * 128 + c], __float_as_uint(v));
}

// ---------------- head: out[g] = pooled[g] @ Wl + bl ----------------

__global__ void k_final(const float* __restrict__ pooled, const float* __restrict__ Wl,
                        const float* __restrict__ bl, float* __restrict__ out) {
    int g = blockIdx.x;
    int t = threadIdx.x;  // 64 threads
    float p0 = pooled[(size_t)g * 128 + t];
    float p1 = pooled[(size_t)g * 128 + t + 64];
    float a0 = p0 * Wl[t * 2 + 0] + p1 * Wl[(t + 64) * 2 + 0];
    float a1 = p0 * Wl[t * 2 + 1] + p1 * Wl[(t + 64) * 2 + 1];
#pragma unroll
    for (int off = 32; off > 0; off >>= 1) {
        a0 += __shfl_down(a0, off);
        a1 += __shfl_down(a1, off);
    }
    if (t == 0) {
        out[g * 2 + 0] = a0 + bl[0];
        out[g * 2 + 1] = a1 + bl[1];
    }
}

// ---------------- launch ----------------

extern "C" void kernel_launch(void* const* d_in, const int* in_sizes, int n_in,
                              void* d_out, int out_size, void* d_ws, size_t ws_size,
                              hipStream_t stream) {
    const float* x  = (const float*)d_in[0];
    const int*   ei = (const int*)d_in[1];
    const int*   batch = (const int*)d_in[2];
    const float* W1 = (const float*)d_in[3];
    const float* b1 = (const float*)d_in[4];
    const float* W2 = (const float*)d_in[5];
    const float* b2 = (const float*)d_in[6];
    const float* W3 = (const float*)d_in[7];
    const float* b3 = (const float*)d_in[8];
    const float* Wl = (const float*)d_in[9];
    const float* bl = (const float*)d_in[10];
    float* out = (float*)d_out;

    const int N = N_NODES, E = N_EDGES;

    // workspace layout
    char* ws = (char*)d_ws;
    __half* bufA = (__half*)ws;                             // N*128 fp16 (hw)
    __half* bufB = bufA + (size_t)N * 128;                  // N*128 fp16 (agg)
    unsigned* pooled = (unsigned*)(bufB + (size_t)N * 128); // G*128
    float* dis  = (float*)(pooled + (size_t)N_GRAPHS * 128);
    float* dinv = dis + N;
    int*   cnt  = (int*)(dinv + N);                         // N
    int*   rowptr = cnt + N;                                // N+1
    int*   cursor = rowptr + N + 2;                         // N
    int*   bsum   = cursor + N;                             // 512
    int*   csrc   = bsum + 512;                             // E
    float* cw     = (float*)(csrc + E);                     // E

    int nb256 = (N + 255) / 256;   // 391
    int eb256 = (E + 255) / 256;   // 6250

    // CSR build + norms
    hipMemsetAsync(cnt, 0, (size_t)N * sizeof(int), stream);
    k_hist<<<eb256, 256, 0, stream>>>(ei + E, E, cnt);
    k_deg_fin<<<nb256, 256, 0, stream>>>(cnt, dis, dinv, N);
    k_scan1<<<nb256, SCAN_B, 0, stream>>>(cnt, rowptr, bsum, N);
    k_scan2<<<1, 512, 0, stream>>>(bsum, nb256);
    k_scan3<<<nb256, SCAN_B, 0, stream>>>(rowptr, bsum, cursor, N, E);
    k_scatter<<<eb256, 256, 0, stream>>>(ei, dis, cursor, csrc, cw, E);

    int ggrid = (N + 3) / 4;
    int mfma_grid = (N + 127) / 128;   // 782

    // layer 1
    k_linear1<<<(N + 1) / 2, 256, 0, stream>>>(x, W1, bufA, N);
    k_gather<<<ggrid, 256, 0, stream>>>(rowptr, csrc, cw, dinv,
                                        (const __half2*)bufA, (__half2*)bufB, N);

    // layer 2
    k_gemm_mfma<<<mfma_grid, 256, 0, stream>>>(bufB, b1, W2, bufA, N);
    k_gather<<<ggrid, 256, 0, stream>>>(rowptr, csrc, cw, dinv,
                                        (const __half2*)bufA, (__half2*)bufB, N);

    // layer 3
    k_gemm_mfma<<<mfma_grid, 256, 0, stream>>>(bufB, b2, W3, bufA, N);
    k_gather<<<ggrid, 256, 0, stream>>>(rowptr, csrc, cw, dinv,
                                        (const __half2*)bufA, (__half2*)bufB, N);

    // pooling
    hipMemsetAsync(pooled, 0, (size_t)N_GRAPHS * 128 * sizeof(unsigned), stream);
    k_pool_max<<<(N * 128 + 255) / 256, 256, 0, stream>>>(bufB, b3, batch, pooled, N);

    // head
    k_final<<<N_GRAPHS, 64, 0, stream>>>((const float*)pooled, Wl, bl, out);
}

// Round 6
// 610.789 us; speedup vs baseline: 6.9205x; 1.0311x over previous
//
#include <hip/hip_runtime.h>
#include <hip/hip_fp16.h>

#define N_NODES 100000
#define N_EDGES 1600000
#define HID 128
#define N_GRAPHS 512
#define SCAN_B 256

typedef _Float16 f16x8 __attribute__((ext_vector_type(8)));
typedef float f32x4 __attribute__((ext_vector_type(4)));

// ---------------- CSR build: histogram / scan / scatter ----------------

__global__ void k_hist(const int* __restrict__ dst, int e, int* __restrict__ cnt) {
    int i = blockIdx.x * 256 + threadIdx.x;
    if (i < e) atomicAdd(&cnt[dst[i]], 1);
}

__global__ void k_deg_fin(const int* __restrict__ cnt, float* __restrict__ dis,
                          float* __restrict__ dinv, int n) {
    int i = blockIdx.x * 256 + threadIdx.x;
    if (i < n) {
        float d = (float)(cnt[i] + 1);   // +1 self-loop
        dis[i] = rsqrtf(d);
        dinv[i] = 1.0f / d;
    }
}

__global__ void k_scan1(const int* __restrict__ cnt, int* __restrict__ pre,
                        int* __restrict__ bsum, int n) {
    __shared__ int s[SCAN_B];
    int t = threadIdx.x;
    int i = blockIdx.x * SCAN_B + t;
    int v = (i < n) ? cnt[i] : 0;
    s[t] = v;
    __syncthreads();
    for (int off = 1; off < SCAN_B; off <<= 1) {
        int u = (t >= off) ? s[t - off] : 0;
        __syncthreads();
        s[t] += u;
        __syncthreads();
    }
    if (i < n) pre[i] = s[t] - v;                     // exclusive
    if (t == SCAN_B - 1) bsum[blockIdx.x] = s[t];     // block total
}

__global__ void k_scan2(int* __restrict__ bsum, int nb) {
    __shared__ int s[512];
    int t = threadIdx.x;
    int v = (t < nb) ? bsum[t] : 0;
    s[t] = v;
    __syncthreads();
    for (int off = 1; off < 512; off <<= 1) {
        int u = (t >= off) ? s[t - off] : 0;
        __syncthreads();
        s[t] += u;
        __syncthreads();
    }
    if (t < nb) bsum[t] = s[t] - v;                   // exclusive
}

__global__ void k_scan3(int* __restrict__ pre, const int* __restrict__ bsum,
                        int* __restrict__ cursor, int n, int e) {
    int i = blockIdx.x * SCAN_B + threadIdx.x;
    if (i < n) {
        int r = pre[i] + bsum[blockIdx.x];
        pre[i] = r;
        cursor[i] = r;
    }
    if (i == 0) pre[n] = e;
}

// scatter: only csrc (4B/edge). cw eliminated: w=dis[s]*dis[d] factored into
// gather as dis[d] * sum(dis[s]*hw[s]) — halves random-write line traffic.
__global__ void k_scatter(const int* __restrict__ ei, int* __restrict__ cursor,
                          int* __restrict__ csrc, int e) {
    int i = blockIdx.x * 256 + threadIdx.x;
    if (i >= e) return;
    int s = ei[i];
    int d = ei[N_EDGES + i];
    int pos = atomicAdd(&cursor[d], 1);
    csrc[pos] = s;
}

// ---------------- layer 1: x (N x 7) @ W1 (7 x 128) -> fp16 ----------------

__global__ void k_linear1(const float* __restrict__ x, const float* __restrict__ W1,
                          __half* __restrict__ hw, int n) {
    __shared__ float W1s[7 * 128];
    int tid = threadIdx.x;
    for (int i = tid; i < 7 * 128; i += 256) W1s[i] = W1[i];
    __syncthreads();
    int node = blockIdx.x * 2 + (tid >> 7);
    if (node >= n) return;
    int c = tid & 127;
    const float* xr = x + (size_t)node * 7;
    float acc = 0.f;
#pragma unroll
    for (int k = 0; k < 7; ++k) acc += xr[k] * W1s[k * 128 + c];
    hw[(size_t)node * 128 + c] = __float2half_rn(acc);
}

// ---------------- gather aggregation (fp16 rows) ----------------
// agg[d] = dinv[d]*hw[d] + dis[d] * sum_s dis[s]*hw[s]
// One wave per node. Cooperative index/weight preload (lane i takes edge i,
// deg<=64 fast path), then __shfl broadcast in the inner loop so the only
// memory ops in the loop are the independent row gathers.

__launch_bounds__(256) __global__
void k_gather(const int* __restrict__ rowptr, const int* __restrict__ csrc,
              const float* __restrict__ dis, const float* __restrict__ dinv,
              const __half2* __restrict__ hw2, __half2* __restrict__ agg2, int n) {
    int node = blockIdx.x * 4 + (threadIdx.x >> 6);
    if (node >= n) return;
    int lane = threadIdx.x & 63;
    int beg = rowptr[node];
    int end = rowptr[node + 1];
    int deg = end - beg;
    float dd = dis[node];
    float di = dinv[node];
    float2 hv = __half22float2(hw2[(size_t)node * 64 + lane]);
    float accx = hv.x * di;
    float accy = hv.y * di;

    // cooperative preload: lane i -> edge beg+i (deg<=64 fast path)
    int sidx = 0;
    float wsc = 0.f;
    if (lane < deg) {
        sidx = csrc[beg + lane];
        wsc = dis[sidx];            // L2-resident 400KB table
    }

    float sx = 0.f, sy = 0.f;
    int m = deg < 64 ? deg : 64;
    int j = 0;
    for (; j + 3 < m; j += 4) {
        int s0 = __shfl(sidx, j);     float w0 = __shfl(wsc, j);
        int s1 = __shfl(sidx, j + 1); float w1 = __shfl(wsc, j + 1);
        int s2 = __shfl(sidx, j + 2); float w2 = __shfl(wsc, j + 2);
        int s3 = __shfl(sidx, j + 3); float w3 = __shfl(wsc, j + 3);
        float2 v0 = __half22float2(hw2[(size_t)s0 * 64 + lane]);
        float2 v1 = __half22float2(hw2[(size_t)s1 * 64 + lane]);
        float2 v2 = __half22float2(hw2[(size_t)s2 * 64 + lane]);
        float2 v3 = __half22float2(hw2[(size_t)s3 * 64 + lane]);
        sx += v0.x * w0 + v1.x * w1 + v2.x * w2 + v3.x * w3;
        sy += v0.y * w0 + v1.y * w1 + v2.y * w2 + v3.y * w3;
    }
    for (; j < m; ++j) {
        int s0 = __shfl(sidx, j);
        float w0 = __shfl(wsc, j);
        float2 v0 = __half22float2(hw2[(size_t)s0 * 64 + lane]);
        sx += v0.x * w0;
        sy += v0.y * w0;
    }
    // rare tail (deg > 64): serial
    for (int jj = beg + 64; jj < end; ++jj) {
        int s0 = csrc[jj];
        float w0 = dis[s0];
        float2 v0 = __half22float2(hw2[(size_t)s0 * 64 + lane]);
        sx += v0.x * w0;
        sy += v0.y * w0;
    }
    accx += dd * sx;
    accy += dd * sy;
    agg2[(size_t)node * 64 + lane] = __floats2half2_rn(accx, accy);
}

// ---------------- MFMA GEMM: hwout = relu(aggin + b) @ W  (fp16 in/out) ----------------
// Block = 256 threads = 4 waves; W^T staged once in LDS, then TWO 64-row
// A-tiles processed (128 rows/block). XOR swizzle kills stride-256B bank
// conflicts for ds_read_b128 fragment loads. Rows >= n zero-filled (no OOB
// read of poisoned ws — R4 lesson).

__device__ __forceinline__ int swz(int row, int kByte) {
    return row * 256 + (kByte ^ ((row & 7) << 4));
}

__launch_bounds__(256) __global__
void k_gemm_mfma(const __half* __restrict__ aggin, const float* __restrict__ b,
                 const float* __restrict__ W, __half* __restrict__ hwout, int n) {
    __shared__ __align__(16) _Float16 Wt[128 * 128];  // 32 KB, Wt[n][k] swizzled
    __shared__ __align__(16) _Float16 As[64 * 128];   // 16 KB, As[m][k] swizzled
    int tid = threadIdx.x;

    for (int i = tid; i < 128 * 128; i += 256) {
        int k = i >> 7;
        int nn = i & 127;
        *(_Float16*)((char*)Wt + swz(nn, k * 2)) = (_Float16)W[i];
    }

    int row = tid >> 2;        // 0..63 (A staging)
    int q = tid & 3;
    int wv = tid >> 6;
    int lane = tid & 63;
    int lo16 = lane & 15;
    int hi4 = lane >> 4;

    for (int t = 0; t < 2; ++t) {
        if (t) __syncthreads();   // all waves done reading As from tile t-1
        int grow = blockIdx.x * 128 + t * 64 + row;
#pragma unroll
        for (int j = 0; j < 4; ++j) {
            int c0 = q * 32 + j * 8;  // half index within row
            uint4 pk = make_uint4(0u, 0u, 0u, 0u);
            if (grow < n) {
                uint4 p = *(const uint4*)(aggin + (size_t)grow * 128 + c0);
                float4 bA = *(const float4*)(b + c0);
                float4 bB = *(const float4*)(b + c0 + 4);
                float2 t0 = __half22float2(*(const __half2*)&p.x);
                float2 t1 = __half22float2(*(const __half2*)&p.y);
                float2 t2 = __half22float2(*(const __half2*)&p.z);
                float2 t3 = __half22float2(*(const __half2*)&p.w);
                __half2 h0 = __floats2half2_rn(fmaxf(t0.x + bA.x, 0.f), fmaxf(t0.y + bA.y, 0.f));
                __half2 h1 = __floats2half2_rn(fmaxf(t1.x + bA.z, 0.f), fmaxf(t1.y + bA.w, 0.f));
                __half2 h2 = __floats2half2_rn(fmaxf(t2.x + bB.x, 0.f), fmaxf(t2.y + bB.y, 0.f));
                __half2 h3 = __floats2half2_rn(fmaxf(t3.x + bB.z, 0.f), fmaxf(t3.y + bB.w, 0.f));
                pk.x = *(unsigned*)&h0; pk.y = *(unsigned*)&h1;
                pk.z = *(unsigned*)&h2; pk.w = *(unsigned*)&h3;
            }
            *(uint4*)((char*)As + swz(row, c0 * 2)) = pk;
        }
        __syncthreads();

        f32x4 acc[8];
#pragma unroll
        for (int nt = 0; nt < 8; ++nt) acc[nt] = (f32x4){0.f, 0.f, 0.f, 0.f};

        const char* Ab = (const char*)As;
        const char* Bb = (const char*)Wt;
#pragma unroll
        for (int kt = 0; kt < 4; ++kt) {
            int kByte = kt * 64 + hi4 * 16;
            f16x8 af = *(const f16x8*)(Ab + swz(wv * 16 + lo16, kByte));
#pragma unroll
            for (int nt = 0; nt < 8; ++nt) {
                f16x8 bf = *(const f16x8*)(Bb + swz(nt * 16 + lo16, kByte));
                acc[nt] = __builtin_amdgcn_mfma_f32_16x16x32_f16(af, bf, acc[nt], 0, 0, 0);
            }
        }

        int rbase = blockIdx.x * 128 + t * 64 + wv * 16 + hi4 * 4;
#pragma unroll
        for (int nt = 0; nt < 8; ++nt) {
#pragma unroll
            for (int r = 0; r < 4; ++r) {
                int node = rbase + r;
                if (node < n)
                    hwout[(size_t)node * 128 + nt * 16 + lo16] = __float2half_rn(acc[nt][r]);
            }
        }
    }
}

// ---------------- pooling: segment_max(relu(agg+b)) via atomicMax on float bits ----------------

__global__ void k_pool_max(const __half* __restrict__ agg, const float* __restrict__ b,
                           const int* __restrict__ batch, unsigned* __restrict__ pooled, int n) {
    int idx = blockIdx.x * 256 + threadIdx.x;
    int node = idx >> 7;
    if (node >= n) return;
    int c = idx & 127;
    int g = batch[node];
    float v = __half2float(agg[(size_t)node * 128 + c]) + b[c];
    v = fmaxf(v, 0.f);
    atomicMax(&pooled[(size_t)g * 128 + c], __float_as_uint(v));
}

// ---------------- head: out[g] = pooled[g] @ Wl + bl ----------------

__global__ void k_final(const float* __restrict__ pooled, const float* __restrict__ Wl,
                        const float* __restrict__ bl, float* __restrict__ out) {
    int g = blockIdx.x;
    int t = threadIdx.x;  // 64 threads
    float p0 = pooled[(size_t)g * 128 + t];
    float p1 = pooled[(size_t)g * 128 + t + 64];
    float a0 = p0 * Wl[t * 2 + 0] + p1 * Wl[(t + 64) * 2 + 0];
    float a1 = p0 * Wl[t * 2 + 1] + p1 * Wl[(t + 64) * 2 + 1];
#pragma unroll
    for (int off = 32; off > 0; off >>= 1) {
        a0 += __shfl_down(a0, off);
        a1 += __shfl_down(a1, off);
    }
    if (t == 0) {
        out[g * 2 + 0] = a0 + bl[0];
        out[g * 2 + 1] = a1 + bl[1];
    }
}

// ---------------- launch ----------------

extern "C" void kernel_launch(void* const* d_in, const int* in_sizes, int n_in,
                              void* d_out, int out_size, void* d_ws, size_t ws_size,
                              hipStream_t stream) {
    const float* x  = (const float*)d_in[0];
    const int*   ei = (const int*)d_in[1];
    const int*   batch = (const int*)d_in[2];
    const float* W1 = (const float*)d_in[3];
    const float* b1 = (const float*)d_in[4];
    const float* W2 = (const float*)d_in[5];
    const float* b2 = (const float*)d_in[6];
    const float* W3 = (const float*)d_in[7];
    const float* b3 = (const float*)d_in[8];
    const float* Wl = (const float*)d_in[9];
    const float* bl = (const float*)d_in[10];
    float* out = (float*)d_out;

    const int N = N_NODES, E = N_EDGES;

    // workspace layout
    char* ws = (char*)d_ws;
    __half* bufA = (__half*)ws;                             // N*128 fp16 (hw)
    __half* bufB = bufA + (size_t)N * 128;                  // N*128 fp16 (agg)
    unsigned* pooled = (unsigned*)(bufB + (size_t)N * 128); // G*128
    float* dis  = (float*)(pooled + (size_t)N_GRAPHS * 128);
    float* dinv = dis + N;
    int*   cnt  = (int*)(dinv + N);                         // N
    int*   rowptr = cnt + N;                                // N+1
    int*   cursor = rowptr + N + 2;                         // N
    int*   bsum   = cursor + N;                             // 512
    int*   csrc   = bsum + 512;                             // E

    int nb256 = (N + 255) / 256;   // 391
    int eb256 = (E + 255) / 256;   // 6250

    // CSR build + norms
    hipMemsetAsync(cnt, 0, (size_t)N * sizeof(int), stream);
    k_hist<<<eb256, 256, 0, stream>>>(ei + E, E, cnt);
    k_deg_fin<<<nb256, 256, 0, stream>>>(cnt, dis, dinv, N);
    k_scan1<<<nb256, SCAN_B, 0, stream>>>(cnt, rowptr, bsum, N);
    k_scan2<<<1, 512, 0, stream>>>(bsum, nb256);
    k_scan3<<<nb256, SCAN_B, 0, stream>>>(rowptr, bsum, cursor, N, E);
    k_scatter<<<eb256, 256, 0, stream>>>(ei, cursor, csrc, E);

    int ggrid = (N + 3) / 4;
    int mfma_grid = (N + 127) / 128;   // 782

    // layer 1
    k_linear1<<<(N + 1) / 2, 256, 0, stream>>>(x, W1, bufA, N);
    k_gather<<<ggrid, 256, 0, stream>>>(rowptr, csrc, dis, dinv,
                                        (const __half2*)bufA, (__half2*)bufB, N);

    // layer 2
    k_gemm_mfma<<<mfma_grid, 256, 0, stream>>>(bufB, b1, W2, bufA, N);
    k_gather<<<ggrid, 256, 0, stream>>>(rowptr, csrc, dis, dinv,
                                        (const __half2*)bufA, (__half2*)bufB, N);

    // layer 3
    k_gemm_mfma<<<mfma_grid, 256, 0, stream>>>(bufB, b2, W3, bufA, N);
    k_gather<<<ggrid, 256, 0, stream>>>(rowptr, csrc, dis, dinv,
                                        (const __half2*)bufA, (__half2*)bufB, N);

    // pooling
    hipMemsetAsync(pooled, 0, (size_t)N_GRAPHS * 128 * sizeof(unsigned), stream);
    k_pool_max<<<(N * 128 + 255) / 256, 256, 0, stream>>>(bufB, b3, batch, pooled, N);

    // head
    k_final<<<N_GRAPHS, 64, 0, stream>>>((const float*)pooled, Wl, bl, out);
}